// Round 5
// baseline (546.843 us; speedup 1.0000x reference)
//
#include <hip/hip_runtime.h>

// Fused gated aggregator:
//   gates = sigmoid(nodes @ Wg + bg); data = nodes @ Wt + bt
//   out[B,D] = owner_masks(float) @ (data * gates)
// v6: nodes staged HBM->LDS via global_load_lds (16B), 3 LDS buffers, depth-2
//     staging, lgkm-only barriers (no vmcnt drain in steady state; counted
//     vmcnt only at pipeline seams). Source-swizzled staging (lane&31 ^ row&7)
//     so linear-dest DMA yields conflict-free swizzled reads. Masks stay
//     reg-resident 1-deep convert-then-reissue. No nf regs -> no spills.

#define NTOT   500000
#define NBLK   512
#define NCHUNK 15625   // NTOT / 32, exact

typedef __attribute__((ext_vector_type(8))) unsigned short ushort8;
typedef __bf16 bf16x8 __attribute__((ext_vector_type(8)));
typedef __bf16 bf16x2 __attribute__((ext_vector_type(2)));
typedef __attribute__((ext_vector_type(4))) float f32x4;

#define GLOAD16(gp, lp)                                                     \
  __builtin_amdgcn_global_load_lds(                                         \
      (const __attribute__((address_space(1))) void*)(gp),                  \
      (__attribute__((address_space(3))) void*)(lp), 16, 0, 0)

// lgkm-only barrier: LDS producer->consumer ordering without draining vmem.
#define BAR_LGKM()                                              \
  do {                                                          \
    asm volatile("s_waitcnt lgkmcnt(0)" ::: "memory");          \
    __builtin_amdgcn_s_barrier();                               \
  } while (0)

// packed f32x2 -> bf16x2 (RNE; lowers to v_cvt_pk_bf16_f32)
static __device__ __forceinline__ unsigned int pkbf(float a, float b) {
  bf16x2 v;
  v[0] = (__bf16)a;
  v[1] = (__bf16)b;
  return __builtin_bit_cast(unsigned int, v);
}

// int 0/1 pair -> packed bf16 {lo,hi}; bf16(1.0) = 0x3F80. 2 cndmask + 1 or.
static __device__ __forceinline__ unsigned int mkw(int lo, int hi) {
  return (lo ? 0x3F80u : 0u) | (hi ? 0x3F800000u : 0u);
}

template <bool ATOMIC>
__global__ __launch_bounds__(512, 4)
void agg_main(const float* __restrict__ nodes, const int* __restrict__ masks,
              const float* __restrict__ Wt, const float* __restrict__ bt,
              const float* __restrict__ Wg, const float* __restrict__ bg,
              float* __restrict__ outp) {
  // nodes: 3 buffers x [32 rows][128 f32], LINEAR (DMA dest), source-swizzled:
  //   physical 16B-block pb holds logical block pb ^ (row&7).
  __shared__ __align__(16) float nodes_f[3 * 4096];            // 48 KiB
  __shared__ __align__(16) unsigned short vt_s[2][128][40];    // 20 KiB

  const int tid = threadIdx.x;
  const int lane = tid & 63;
  const int w = tid >> 6;    // wave 0..7
  const int q = lane >> 4;   // quad 0..3
  const int r = lane & 15;

  // ---- preload W as B-operand fragments (reg-resident), + biases ----
  // wave w owns d-slice [w*16, w*16+16). B-frag: n = lane&15, k = quad*8 + j
  bf16x8 Wf[2][4];  // [data/gate][ks] -- 32 regs (acc-file)
  const int dslc = w * 16 + r;
  const float btr = bt[dslc];
  const float bgr = bg[dslc];
#pragma unroll
  for (int ks = 0; ks < 4; ++ks) {
    ushort8 ft, fg;
#pragma unroll
    for (int j = 0; j < 8; ++j) {
      const int k = ks * 32 + q * 8 + j;  // s index
      ft[j] = __builtin_bit_cast(unsigned short, (__bf16)Wt[k * 128 + dslc]);
      fg[j] = __builtin_bit_cast(unsigned short, (__bf16)Wg[k * 128 + dslc]);
    }
    Wf[0][ks] = __builtin_bit_cast(bf16x8, ft);
    Wf[1][ks] = __builtin_bit_cast(bf16x8, fg);
  }

  // pooling accumulators: wave w owns out rows [w*16, w*16+16) x ALL 128 cols
  f32x4 acc[8];  // 32 regs (acc-file)
  const f32x4 fzero = {0.f, 0.f, 0.f, 0.f};
#pragma unroll
  for (int j = 0; j < 8; ++j) acc[j] = fzero;

  const int bid = blockIdx.x;
  const int c0 = (int)(((long long)bid * NCHUNK) / NBLK);
  const int c1 = (int)(((long long)(bid + 1) * NCHUNK) / NBLK);
  const int n = c1 - c0;

  // 32-bit mask element offset (masks buffer = 256 MB)
  const unsigned moff = (unsigned)(w * 16 + r) * (unsigned)NTOT + (unsigned)(q * 8);
  int4 mi[2];  // mask prefetch (single set, convert-then-reissue)

  // per-lane swizzled global source byte-offsets within a 16 KiB chunk:
  // instruction it covers rows (w*2+it)*2 + (lane>>5), physical block lane&31;
  // source logical block = (lane&31) ^ (row&7).
  const int row0 = (w * 2 + 0) * 2 + (lane >> 5);
  const int row1 = (w * 2 + 1) * 2 + (lane >> 5);
  const unsigned tb0 = (unsigned)(row0 * 512 + (((lane & 31) ^ (row0 & 7)) << 4));
  const unsigned tb1 = (unsigned)(row1 * 512 + (((lane & 31) ^ (row1 & 7)) << 4));

  auto issue_gload = [&](unsigned fbase, int c) {
    const char* gp = (const char*)nodes + (size_t)c * 16384u;
    GLOAD16(gp + tb0, &nodes_f[fbase + (unsigned)(w * 2 + 0) * 256u]);
    GLOAD16(gp + tb1, &nodes_f[fbase + (unsigned)(w * 2 + 1) * 256u]);
  };

  auto issue_masks = [&](int c) {
    const unsigned o = moff + (unsigned)c * 32u;
    mi[0] = *(const int4*)(masks + o);
    mi[1] = *(const int4*)(masks + o + 4);
  };

  // A-frag from swizzled fp32 LDS: row = rowbase + r, logical blocks
  // lb0 = ks*8+q*2, lb0+1; physical = lb ^ (r&7). Convert to bf16x8.
  auto frag = [&](unsigned fbase, int rowbase, int ks) -> bf16x8 {
    const int row = rowbase + r;
    const int s7 = r & 7;
    const int lb0 = ks * 8 + q * 2;
    const f32x4 v0 = *(const f32x4*)&nodes_f[fbase + (unsigned)(row * 128) +
                                             (unsigned)(((lb0 + 0) ^ s7) << 2)];
    const f32x4 v1 = *(const f32x4*)&nodes_f[fbase + (unsigned)(row * 128) +
                                             (unsigned)(((lb0 + 1) ^ s7) << 2)];
    uint4 u;
    u.x = pkbf(v0[0], v0[1]);
    u.y = pkbf(v0[2], v0[3]);
    u.z = pkbf(v1[0], v1[1]);
    u.w = pkbf(v1[2], v1[3]);
    return __builtin_bit_cast(bf16x8, u);
  };

  // pooling: out[b][d] += mask[b][node] * V[node][d], K=32 (8 MFMA/wave).
  // Converts mi -> packed bf16, then reissues mi for chunk cnext.
  // Side effect (pipeline invariant): waiting on mi's regs forces all OLDER
  // vmem ops -- incl. the gloads for the NEXT chunk's buffer -- to complete
  // in this wave before the end-of-body barrier.
  auto pool_reissue = [&](int vbuf, int cnext) {
    uint4 u;
    u.x = mkw(mi[0].x, mi[0].y);
    u.y = mkw(mi[0].z, mi[0].w);
    u.z = mkw(mi[1].x, mi[1].y);
    u.w = mkw(mi[1].z, mi[1].w);
    issue_masks(cnext);
    const bf16x8 af = __builtin_bit_cast(bf16x8, u);
#pragma unroll
    for (int nt = 0; nt < 8; ++nt) {
      const bf16x8 bfr = *(const bf16x8*)&vt_s[vbuf][nt * 16 + r][q * 8];
      acc[nt] = __builtin_amdgcn_mfma_f32_16x16x32_bf16(af, bfr, acc[nt], 0, 0, 0);
    }
  };

  auto pool_last = [&](int vbuf) {
    uint4 u;
    u.x = mkw(mi[0].x, mi[0].y);
    u.y = mkw(mi[0].z, mi[0].w);
    u.z = mkw(mi[1].x, mi[1].y);
    u.w = mkw(mi[1].z, mi[1].w);
    const bf16x8 af = __builtin_bit_cast(bf16x8, u);
#pragma unroll
    for (int nt = 0; nt < 8; ++nt) {
      const bf16x8 bfr = *(const bf16x8*)&vt_s[vbuf][nt * 16 + r][q * 8];
      acc[nt] = __builtin_amdgcn_mfma_f32_16x16x32_bf16(af, bfr, acc[nt], 0, 0, 0);
    }
  };

  // GEMM1 [32 x 128s] @ W[128s x 16d-slice] + gated epilogue -> vt_s[vbuf]
  auto gemm_epi = [&](unsigned fbase, int vbuf) {
    f32x4 aD[2], aG[2];  // [mt]
    aD[0] = fzero; aD[1] = fzero; aG[0] = fzero; aG[1] = fzero;
#pragma unroll
    for (int ks = 0; ks < 4; ++ks) {
      const bf16x8 a0 = frag(fbase, 0, ks);
      const bf16x8 a1 = frag(fbase, 16, ks);
      aD[0] = __builtin_amdgcn_mfma_f32_16x16x32_bf16(a0, Wf[0][ks], aD[0], 0, 0, 0);
      aD[1] = __builtin_amdgcn_mfma_f32_16x16x32_bf16(a1, Wf[0][ks], aD[1], 0, 0, 0);
      aG[0] = __builtin_amdgcn_mfma_f32_16x16x32_bf16(a0, Wf[1][ks], aG[0], 0, 0, 0);
      aG[1] = __builtin_amdgcn_mfma_f32_16x16x32_bf16(a1, Wf[1][ks], aG[1], 0, 0, 0);
    }
    // epilogue: V = (data+bt)*sigmoid(gate+bg); write V^T[d][node]
    // C/D layout: col = lane&15, row = quad*4 + reg
#pragma unroll
    for (int mt = 0; mt < 2; ++mt) {
      float v[4];
#pragma unroll
      for (int reg = 0; reg < 4; ++reg) {
        const float x = aD[mt][reg] + btr;
        const float g = aG[mt][reg] + bgr;
        v[reg] = x * __builtin_amdgcn_rcpf(1.f + __expf(-g));
      }
      uint2 u;
      u.x = pkbf(v[0], v[1]);
      u.y = pkbf(v[2], v[3]);
      *(uint2*)&vt_s[vbuf][dslc][mt * 16 + q * 4] = u;
    }
  };

  // ---- pipeline ----
  // Buffers rotate cur -> nxt -> nx2 (float offsets 0/4096/8192); vt parity vb.
  unsigned cur = 0, nxt = 4096, nx2 = 8192;
  int vb = 0;

  // prologue: stage chunks c0, c0+1 (dup c0 if n==1), masks c0.
  issue_gload(cur, c0);
  issue_gload(nxt, n > 1 ? c0 + 1 : c0);
  issue_masks(c0);
  // force g(c0) complete (leave g(c0+1) + masks in flight), then barrier.
  asm volatile("s_waitcnt vmcnt(4)" ::: "memory");
  __builtin_amdgcn_s_barrier();

  // body 0 (no pool)
  if (2 < n) issue_gload(nx2, c0 + 2);
  gemm_epi(cur, 0);
  if (n > 1) {
    // seam: body 0 has no pool-wait, so force g(c0+1) before entering body 1.
    if (n > 2) asm volatile("s_waitcnt vmcnt(4) lgkmcnt(0)" ::: "memory");
    else       asm volatile("s_waitcnt vmcnt(2) lgkmcnt(0)" ::: "memory");
    __builtin_amdgcn_s_barrier();
  }
  { unsigned t = cur; cur = nxt; nxt = nx2; nx2 = t; }
  vb = 1;

  for (int i = 1; i < n; ++i) {
    if (i + 2 < n) issue_gload(nx2, c0 + i + 2);
    pool_reissue(vb ^ 1, c0 + i);  // pools chunk i-1; reissues mi <- chunk i
    gemm_epi(cur, vb);
    if (i + 1 < n) BAR_LGKM();     // g(c_{i+1}) already done via pool's mi-wait
    { unsigned t = cur; cur = nxt; nxt = nx2; nx2 = t; }
    vb ^= 1;
  }

  BAR_LGKM();
  pool_last((n - 1) & 1);  // mi holds chunk n-1

  // ---- write per-block partial (or atomic accumulate) ----
#pragma unroll
  for (int nt = 0; nt < 8; ++nt)
#pragma unroll
    for (int reg = 0; reg < 4; ++reg) {
      const int b = w * 16 + q * 4 + reg;
      const int d = nt * 16 + r;
      if (ATOMIC)
        atomicAdd(&outp[b * 128 + d], acc[nt][reg]);
      else
        outp[(size_t)bid * 16384 + b * 128 + d] = acc[nt][reg];
    }
}

__global__ __launch_bounds__(256)
void agg_reduce(const float* __restrict__ part, float* __restrict__ out) {
  // 128 blocks x 256 thr = 32768 = 8 groups x 4096 float4 outputs; 64 partials each
  const int gid = blockIdx.x * 256 + threadIdx.x;
  const int i4 = gid & 4095;
  const int grp = gid >> 12;
  const float4* p = (const float4*)part + (size_t)grp * 64 * 4096 + i4;
  float4 s = {0.f, 0.f, 0.f, 0.f};
#pragma unroll 8
  for (int g = 0; g < 64; ++g) {
    const float4 v = p[(size_t)g * 4096];
    s.x += v.x; s.y += v.y; s.z += v.z; s.w += v.w;
  }
  atomicAdd(&out[i4 * 4 + 0], s.x);
  atomicAdd(&out[i4 * 4 + 1], s.y);
  atomicAdd(&out[i4 * 4 + 2], s.z);
  atomicAdd(&out[i4 * 4 + 3], s.w);
}

extern "C" void kernel_launch(void* const* d_in, const int* in_sizes, int n_in,
                              void* d_out, int out_size, void* d_ws, size_t ws_size,
                              hipStream_t stream) {
  const float* nodes = (const float*)d_in[0];
  const int*   masks = (const int*)d_in[1];
  const float* Wt    = (const float*)d_in[2];
  const float* bt    = (const float*)d_in[3];
  const float* Wg    = (const float*)d_in[4];
  const float* bg    = (const float*)d_in[5];
  float* out = (float*)d_out;

  hipMemsetAsync(d_out, 0, (size_t)out_size * sizeof(float), stream);

  const size_t need = (size_t)NBLK * 16384 * sizeof(float);
  if (ws_size >= need) {
    agg_main<false><<<NBLK, 512, 0, stream>>>(nodes, masks, Wt, bt, Wg, bg, (float*)d_ws);
    agg_reduce<<<128, 256, 0, stream>>>((const float*)d_ws, out);
  } else {
    agg_main<true><<<NBLK, 512, 0, stream>>>(nodes, masks, Wt, bt, Wg, bg, out);
  }
}